// Round 5
// baseline (389.035 us; speedup 1.0000x reference)
//
#include <hip/hip_runtime.h>
#include <stdint.h>

#define S_DIM 8192
#define IN_DIM 4096
#define OUT_DIM 4096
#define K_EXT 128
#define SCALING 0.5f

typedef __attribute__((ext_vector_type(4))) float f32x4;
typedef __attribute__((ext_vector_type(8))) __bf16 bf16x8;

__device__ __forceinline__ unsigned short f2bf(float f) {
    union { float f; uint32_t u; } v; v.f = f;
    uint32_t u = v.u;
    u += 0x7fffu + ((u >> 16) & 1u);   // RNE
    return (unsigned short)(u >> 16);
}

// ---------------- Kernel 1: f32 -> bf16 (grid-stride; used for W and A) ----------------
__global__ __launch_bounds__(256) void convert_w(const float* __restrict__ in,
                                                 unsigned short* __restrict__ out, int n4) {
    int i = blockIdx.x * blockDim.x + threadIdx.x;
    int stride = gridDim.x * blockDim.x;
    for (; i < n4; i += stride) {
        float4 v = ((const float4*)in)[i];
        ushort4 o;
        o.x = f2bf(v.x); o.y = f2bf(v.y); o.z = f2bf(v.z); o.w = f2bf(v.w);
        ((ushort4*)out)[i] = o;
    }
}

// ---------------- Kernel 2: we[o][a*16+r] = bf16(0.5 * B[a][o][r]) ----------------
__global__ __launch_bounds__(256) void build_we(const float* __restrict__ B,
                                                unsigned short* __restrict__ we) {
    int i = blockIdx.x * 256 + threadIdx.x;   // 0..32767 -> (o, a)
    int o = i >> 3, a = i & 7;
    const float* src = B + ((size_t)a * OUT_DIM + o) * 16;
    unsigned short* dst = we + (size_t)o * K_EXT + a * 16;
#pragma unroll
    for (int r = 0; r < 16; r += 4) {
        float4 v = *(const float4*)(src + r);
        ushort4 u;
        u.x = f2bf(SCALING * v.x); u.y = f2bf(SCALING * v.y);
        u.z = f2bf(SCALING * v.z); u.w = f2bf(SCALING * v.w);
        *(ushort4*)(dst + r) = u;
    }
}

// ------- Kernel 3: x f32->bf16 + xe[s][a*16+r] = (a==widx[s]) ? x[s,:].A[a,r,:] : 0 -------
// 256 blocks x 32 tokens; 8 waves: wr=w&1 (token half), wc=w>>1 (adapter quarter)
__global__ __launch_bounds__(512) void xak(const float* __restrict__ x,
                                           const unsigned short* __restrict__ Abf,
                                           const int* __restrict__ widx,
                                           unsigned short* __restrict__ xbf,
                                           unsigned short* __restrict__ xe) {
    __shared__ unsigned short xs[32 * 64];    // 4 KB, swizzled
    __shared__ unsigned short as_[128 * 64];  // 16 KB, swizzled
    int s0 = blockIdx.x * 32;
    int t = threadIdx.x;
    int lane = t & 63, w = t >> 6;
    int wr = w & 1, wc = w >> 1;
    int frow = lane & 15, koct = lane >> 4;

    f32x4 acc[2];
#pragma unroll
    for (int n = 0; n < 2; ++n)
#pragma unroll
        for (int j = 0; j < 4; ++j) acc[n][j] = 0.f;

    int xrow = t >> 4, xf4 = t & 15;
    const float* xsrc = x + (size_t)(s0 + xrow) * IN_DIM + xf4 * 4;
    unsigned short* xdst = xbf + (size_t)(s0 + xrow) * IN_DIM + xf4 * 4;
    int xsd = xrow * 64 + ((xf4 * 4) ^ ((xrow & 7) << 3));

    for (int kt = 0; kt < 64; ++kt) {
        int k0 = kt * 64;
        __syncthreads();
        {
            float4 xv = *(const float4*)(xsrc + k0);
            ushort4 o;
            o.x = f2bf(xv.x); o.y = f2bf(xv.y); o.z = f2bf(xv.z); o.w = f2bf(xv.w);
            *(ushort4*)(xdst + k0) = o;
            *(ushort4*)&xs[xsd] = o;
        }
#pragma unroll
        for (int i = 0; i < 2; ++i) {
            int c = i * 512 + t;
            int aj = c >> 3, ch = c & 7;
            bf16x8 av = *(const bf16x8*)(Abf + (size_t)aj * IN_DIM + k0 + ch * 8);
            *(bf16x8*)&as_[aj * 64 + ((ch ^ (aj & 7)) << 3)] = av;
        }
        __syncthreads();
        bf16x8 xf[2], af[2][2];
#pragma unroll
        for (int ks = 0; ks < 2; ++ks) {
            int r = wr * 16 + frow;
            int ch = koct + ks * 4;
            xf[ks] = *(const bf16x8*)&xs[r * 64 + ((ch ^ (r & 7)) << 3)];
        }
#pragma unroll
        for (int nn = 0; nn < 2; ++nn)
#pragma unroll
            for (int ks = 0; ks < 2; ++ks) {
                int rj = wc * 32 + nn * 16 + frow;
                int ch = koct + ks * 4;
                af[nn][ks] = *(const bf16x8*)&as_[rj * 64 + ((ch ^ (rj & 7)) << 3)];
            }
#pragma unroll
        for (int nn = 0; nn < 2; ++nn)
#pragma unroll
            for (int ks = 0; ks < 2; ++ks)
                acc[nn] = __builtin_amdgcn_mfma_f32_16x16x32_bf16(xf[ks], af[nn][ks], acc[nn], 0, 0, 0);
    }
    // write expanded xe (each (s, slot) exactly once across the block)
#pragma unroll
    for (int rg = 0; rg < 4; ++rg) {
        int s = s0 + wr * 16 + koct * 4 + rg;
        int aidx = widx[s];
#pragma unroll
        for (int nn = 0; nn < 2; ++nn) {
            int a = wc * 2 + nn;
            unsigned short v = (a == aidx) ? f2bf(acc[nn][rg]) : (unsigned short)0;
            xe[(size_t)s * K_EXT + a * 16 + frow] = v;
        }
    }
}

// ---------------- Kernel 4: 256x256 bf16 MFMA GEMM over K=4224, counted-vmcnt ----------------
__device__ __forceinline__ void gload_lds16(const void* g, void* l) {
    __builtin_amdgcn_global_load_lds(
        (const __attribute__((address_space(1))) unsigned int*)(uintptr_t)g,
        (__attribute__((address_space(3))) unsigned int*)(unsigned int)(uintptr_t)l,
        16, 0, 0);
}

#define VM4 asm volatile("s_waitcnt vmcnt(4)" ::: "memory")
#define VM2 asm volatile("s_waitcnt vmcnt(2)" ::: "memory")
#define VM0 asm volatile("s_waitcnt vmcnt(0)" ::: "memory")
#define VMNOP do {} while (0)
#define BAR do { __builtin_amdgcn_s_barrier(); asm volatile("" ::: "memory"); } while (0)

__global__ __launch_bounds__(512, 2) void gemm256(const unsigned short* __restrict__ Xb,
                                                  const unsigned short* __restrict__ Wb,
                                                  const unsigned short* __restrict__ Xe,
                                                  const unsigned short* __restrict__ We,
                                                  const float* __restrict__ bias,
                                                  float* __restrict__ out) {
    extern __shared__ unsigned short lds[];

    const int nT = 512;                      // 32 x 16 tiles, %8==0 -> bijective XCD swizzle
    int bid = blockIdx.x;
    int swz = (bid & 7) * (nT >> 3) + (bid >> 3);
    int tm = swz >> 4, tn = swz & 15;
    int rowBase = tm * 256, colBase = tn * 256;

    int t = threadIdx.x;
    int lane = t & 63;
    int wid = t >> 6;
    int wm = wid >> 2;                       // 0..1 -> 128 rows
    int wn = wid & 3;                        // 0..3 -> 64 cols
    int frow = lane & 15;
    int koct = lane >> 4;
    int wmBase = wm * 128, wnBase = wn * 64;

    // staging: thread t -> row t>>3, dest chunk t&7; global source chunk (t&7)^(row&7)
    int srow = t >> 3;
    int schunk = ((t & 7) ^ (srow & 7)) << 3;
    const unsigned short* srcA0 = Xb + (size_t)(rowBase + srow) * IN_DIM + schunk;
    const unsigned short* srcB0 = Wb + (size_t)(colBase + srow) * IN_DIM + schunk;
    const unsigned short* srcAe = Xe + (size_t)(rowBase + srow) * K_EXT + schunk;
    const unsigned short* srcBe = We + (size_t)(colBase + srow) * K_EXT + schunk;

    f32x4 acc[8][4];
#pragma unroll
    for (int m = 0; m < 8; m++)
#pragma unroll
        for (int n = 0; n < 4; n++)
#pragma unroll
            for (int j = 0; j < 4; j++) acc[m][n][j] = 0.f;

#define RD_A(P_, MH, KS, DST) \
    _Pragma("unroll") for (int mm = 0; mm < 4; ++mm) { \
      int r_ = wmBase + (MH) * 64 + mm * 16 + frow; \
      int ch_ = ((KS) * 4 + koct) ^ (r_ & 7); \
      DST[mm] = *(const bf16x8*)&lds[(P_) * 32768 + r_ * 64 + ch_ * 8]; \
    }
#define RD_B(P_, KS, DST) \
    _Pragma("unroll") for (int nn = 0; nn < 4; ++nn) { \
      int r_ = wnBase + nn * 16 + frow; \
      int ch_ = ((KS) * 4 + koct) ^ (r_ & 7); \
      DST[nn] = *(const bf16x8*)&lds[(P_) * 32768 + 16384 + r_ * 64 + ch_ * 8]; \
    }
#define MFMA16(AF, BF, MH) \
    __builtin_amdgcn_s_setprio(1); \
    _Pragma("unroll") for (int mm = 0; mm < 4; ++mm) \
      _Pragma("unroll") for (int nn = 0; nn < 4; ++nn) \
        acc[(MH) * 4 + mm][nn] = __builtin_amdgcn_mfma_f32_16x16x32_bf16( \
            AF[mm], BF[nn], acc[(MH) * 4 + mm][nn], 0, 0, 0); \
    __builtin_amdgcn_s_setprio(0);

// Stage tile KT_ (0..65) into buffer Q_; split across ph0 (first 4) / ph1 (last 4).
// vmcnt invariant: entering a tile, 2 loads (its A1,A3) outstanding; ph0 VM4 publishes them;
// ph3 VM2 publishes next tile's first 6.
#define TILE(P_, Q_, KT_, STG_, VMA_, VMB_) do { \
    bf16x8 a0_[4], a1_[4], b0_[4], b1_[4]; \
    const unsigned short *sa_ = srcA0, *sb_ = srcB0; size_t gs_ = (size_t)64 * IN_DIM; int ko_ = (KT_) * 64; \
    if ((STG_) && (KT_) >= 64) { sa_ = srcAe; sb_ = srcBe; gs_ = 64 * K_EXT; ko_ = ((KT_) - 64) * 64; } \
    RD_A(P_, 0, 0, a0_); RD_B(P_, 0, b0_); \
    if (STG_) { gload_lds16(sa_ + ko_,            &lds[(Q_) * 32768 + t * 8]); \
                gload_lds16(sa_ + ko_ + 2 * gs_,  &lds[(Q_) * 32768 + 8192 + t * 8]); \
                gload_lds16(sb_ + ko_,            &lds[(Q_) * 32768 + 16384 + t * 8]); \
                gload_lds16(sb_ + ko_ + gs_,      &lds[(Q_) * 32768 + 16384 + 4096 + t * 8]); } \
    VMA_; BAR; MFMA16(a0_, b0_, 0); BAR; \
    RD_A(P_, 1, 0, a1_); \
    if (STG_) { gload_lds16(sb_ + ko_ + 2 * gs_,  &lds[(Q_) * 32768 + 16384 + 8192 + t * 8]); \
                gload_lds16(sb_ + ko_ + 3 * gs_,  &lds[(Q_) * 32768 + 16384 + 12288 + t * 8]); \
                gload_lds16(sa_ + ko_ + gs_,      &lds[(Q_) * 32768 + 4096 + t * 8]); \
                gload_lds16(sa_ + ko_ + 3 * gs_,  &lds[(Q_) * 32768 + 12288 + t * 8]); } \
    BAR; MFMA16(a1_, b0_, 1); BAR; \
    RD_A(P_, 0, 1, a0_); RD_B(P_, 1, b1_); \
    BAR; MFMA16(a0_, b1_, 0); BAR; \
    RD_A(P_, 1, 1, a1_); \
    VMB_; BAR; MFMA16(a1_, b1_, 1); BAR; \
  } while (0)

    // prologue: stage tile 0 into buf 0 (order A0,A2,B0..B3,A1,A3), publish first 6
    gload_lds16(srcA0,                         &lds[t * 8]);
    gload_lds16(srcA0 + (size_t)128 * IN_DIM,  &lds[8192 + t * 8]);
    gload_lds16(srcB0,                         &lds[16384 + t * 8]);
    gload_lds16(srcB0 + (size_t)64 * IN_DIM,   &lds[16384 + 4096 + t * 8]);
    gload_lds16(srcB0 + (size_t)128 * IN_DIM,  &lds[16384 + 8192 + t * 8]);
    gload_lds16(srcB0 + (size_t)192 * IN_DIM,  &lds[16384 + 12288 + t * 8]);
    gload_lds16(srcA0 + (size_t)64 * IN_DIM,   &lds[4096 + t * 8]);
    gload_lds16(srcA0 + (size_t)192 * IN_DIM,  &lds[12288 + t * 8]);
    VM2; BAR;

    int kt = 0;
#pragma unroll 1
    for (int it = 0; it < 32; ++it) {        // tiles 0..63, staging 1..64
        TILE(0, 1, kt + 1, 1, VM4, VM2); ++kt;
        TILE(1, 0, kt + 1, 1, VM4, VM2); ++kt;
    }
    TILE(0, 1, 65, 1, VM4, VM2);             // tile 64 (ext), stages 65
    TILE(1, 0, 0, 0, VM0, VMNOP);            // tile 65 (ext), last

    // ---- epilogue: out = acc + bias ----
    int rquad = koct << 2;
    float biasv[4];
#pragma unroll
    for (int n = 0; n < 4; n++) biasv[n] = bias[colBase + wnBase + n * 16 + frow];

#pragma unroll
    for (int m = 0; m < 8; m++) {
#pragma unroll
        for (int rg = 0; rg < 4; rg++) {
            int lr = wmBase + (m >> 2) * 64 + (m & 3) * 16 + rquad + rg;
            float* orow = out + (size_t)(rowBase + lr) * OUT_DIM;
#pragma unroll
            for (int n = 0; n < 4; n++) {
                int lc = wnBase + n * 16 + frow;
                orow[colBase + lc] = acc[m][n][rg] + biasv[n];
            }
        }
    }
}

extern "C" void kernel_launch(void* const* d_in, const int* in_sizes, int n_in,
                              void* d_out, int out_size, void* d_ws, size_t ws_size,
                              hipStream_t stream) {
    const float* x = (const float*)d_in[0];
    const float* W = (const float*)d_in[1];
    const float* bias = (const float*)d_in[2];
    const float* Abuf = (const float*)d_in[3];
    const float* Bbuf = (const float*)d_in[4];   // [1, A, OUT, R]
    const int* widx = (const int*)d_in[5];
    float* out = (float*)d_out;

    size_t xbf_elems = (size_t)S_DIM * IN_DIM;
    size_t wbf_elems = (size_t)OUT_DIM * IN_DIM;
    size_t abf_elems = (size_t)8 * 16 * IN_DIM;
    size_t xe_elems = (size_t)S_DIM * K_EXT;
    size_t we_elems = (size_t)OUT_DIM * K_EXT;
    size_t need = (xbf_elems + wbf_elems + abf_elems + xe_elems + we_elems) * 2;
    if (ws_size < need) return;

    unsigned short* xbf = (unsigned short*)d_ws;
    unsigned short* wbf = xbf + xbf_elems;
    unsigned short* abf = wbf + wbf_elems;
    unsigned short* xe = abf + abf_elems;
    unsigned short* we = xe + xe_elems;

    hipFuncSetAttribute(reinterpret_cast<const void*>(gemm256),
                        hipFuncAttributeMaxDynamicSharedMemorySize, 131072);

    convert_w<<<2048, 256, 0, stream>>>(W, wbf, (int)(wbf_elems / 4));
    convert_w<<<512, 256, 0, stream>>>(Abuf, abf, (int)(abf_elems / 4));
    build_we<<<128, 256, 0, stream>>>(Bbuf, we);
    xak<<<256, 512, 0, stream>>>(x, abf, widx, xbf, xe);
    gemm256<<<512, 512, 131072, stream>>>(xbf, wbf, xe, we, bias, out);
}

// Round 6
// 329.371 us; speedup vs baseline: 1.1811x; 1.1811x over previous
//
#include <hip/hip_runtime.h>
#include <stdint.h>

#define S_DIM 8192
#define IN_DIM 4096
#define OUT_DIM 4096
#define K_EXT 128
#define SCALING 0.5f

typedef __attribute__((ext_vector_type(4))) float f32x4;
typedef __attribute__((ext_vector_type(8))) __bf16 bf16x8;

__device__ __forceinline__ unsigned short f2bf(float f) {
    union { float f; uint32_t u; } v; v.f = f;
    uint32_t u = v.u;
    u += 0x7fffu + ((u >> 16) & 1u);   // RNE
    return (unsigned short)(u >> 16);
}

// ---------------- Kernel 1: f32 -> bf16 (grid-stride; used for W and A) ----------------
__global__ __launch_bounds__(256) void convert_w(const float* __restrict__ in,
                                                 unsigned short* __restrict__ out, int n4) {
    int i = blockIdx.x * blockDim.x + threadIdx.x;
    int stride = gridDim.x * blockDim.x;
    for (; i < n4; i += stride) {
        float4 v = ((const float4*)in)[i];
        ushort4 o;
        o.x = f2bf(v.x); o.y = f2bf(v.y); o.z = f2bf(v.z); o.w = f2bf(v.w);
        ((ushort4*)out)[i] = o;
    }
}

// ---------------- Kernel 2: we[o][a*16+r] = bf16(0.5 * B[a][o][r]) ----------------
__global__ __launch_bounds__(256) void build_we(const float* __restrict__ B,
                                                unsigned short* __restrict__ we) {
    int i = blockIdx.x * 256 + threadIdx.x;   // 0..32767 -> (o, a)
    int o = i >> 3, a = i & 7;
    const float* src = B + ((size_t)a * OUT_DIM + o) * 16;
    unsigned short* dst = we + (size_t)o * K_EXT + a * 16;
#pragma unroll
    for (int r = 0; r < 16; r += 4) {
        float4 v = *(const float4*)(src + r);
        ushort4 u;
        u.x = f2bf(SCALING * v.x); u.y = f2bf(SCALING * v.y);
        u.z = f2bf(SCALING * v.z); u.w = f2bf(SCALING * v.w);
        *(ushort4*)(dst + r) = u;
    }
}

// ------- Kernel 3: x f32->bf16 + xe[s][a*16+r] = (a==widx[s]) ? x[s,:].A[a,r,:] : 0 -------
__global__ __launch_bounds__(512) void xak(const float* __restrict__ x,
                                           const unsigned short* __restrict__ Abf,
                                           const int* __restrict__ widx,
                                           unsigned short* __restrict__ xbf,
                                           unsigned short* __restrict__ xe) {
    __shared__ unsigned short xs[32 * 64];    // 4 KB, swizzled
    __shared__ unsigned short as_[128 * 64];  // 16 KB, swizzled
    int s0 = blockIdx.x * 32;
    int t = threadIdx.x;
    int lane = t & 63, w = t >> 6;
    int wr = w & 1, wc = w >> 1;
    int frow = lane & 15, koct = lane >> 4;

    f32x4 acc[2];
#pragma unroll
    for (int n = 0; n < 2; ++n)
#pragma unroll
        for (int j = 0; j < 4; ++j) acc[n][j] = 0.f;

    int xrow = t >> 4, xf4 = t & 15;
    const float* xsrc = x + (size_t)(s0 + xrow) * IN_DIM + xf4 * 4;
    unsigned short* xdst = xbf + (size_t)(s0 + xrow) * IN_DIM + xf4 * 4;
    int xsd = xrow * 64 + ((xf4 * 4) ^ ((xrow & 7) << 3));

    for (int kt = 0; kt < 64; ++kt) {
        int k0 = kt * 64;
        __syncthreads();
        {
            float4 xv = *(const float4*)(xsrc + k0);
            ushort4 o;
            o.x = f2bf(xv.x); o.y = f2bf(xv.y); o.z = f2bf(xv.z); o.w = f2bf(xv.w);
            *(ushort4*)(xdst + k0) = o;
            *(ushort4*)&xs[xsd] = o;
        }
#pragma unroll
        for (int i = 0; i < 2; ++i) {
            int c = i * 512 + t;
            int aj = c >> 3, ch = c & 7;
            bf16x8 av = *(const bf16x8*)(Abf + (size_t)aj * IN_DIM + k0 + ch * 8);
            *(bf16x8*)&as_[aj * 64 + ((ch ^ (aj & 7)) << 3)] = av;
        }
        __syncthreads();
        bf16x8 xf[2], af[2][2];
#pragma unroll
        for (int ks = 0; ks < 2; ++ks) {
            int r = wr * 16 + frow;
            int ch = koct + ks * 4;
            xf[ks] = *(const bf16x8*)&xs[r * 64 + ((ch ^ (r & 7)) << 3)];
        }
#pragma unroll
        for (int nn = 0; nn < 2; ++nn)
#pragma unroll
            for (int ks = 0; ks < 2; ++ks) {
                int rj = wc * 32 + nn * 16 + frow;
                int ch = koct + ks * 4;
                af[nn][ks] = *(const bf16x8*)&as_[rj * 64 + ((ch ^ (rj & 7)) << 3)];
            }
#pragma unroll
        for (int nn = 0; nn < 2; ++nn)
#pragma unroll
            for (int ks = 0; ks < 2; ++ks)
                acc[nn] = __builtin_amdgcn_mfma_f32_16x16x32_bf16(xf[ks], af[nn][ks], acc[nn], 0, 0, 0);
    }
#pragma unroll
    for (int rg = 0; rg < 4; ++rg) {
        int s = s0 + wr * 16 + koct * 4 + rg;
        int aidx = widx[s];
#pragma unroll
        for (int nn = 0; nn < 2; ++nn) {
            int a = wc * 2 + nn;
            unsigned short v = (a == aidx) ? f2bf(acc[nn][rg]) : (unsigned short)0;
            xe[(size_t)s * K_EXT + a * 16 + frow] = v;
        }
    }
}

// ---------------- Kernel 4: 256x256 bf16 MFMA GEMM over K=4224, counted-vmcnt ----------------
__device__ __forceinline__ void gload_lds16(const void* g, void* l) {
    __builtin_amdgcn_global_load_lds(
        (const __attribute__((address_space(1))) unsigned int*)(uintptr_t)g,
        (__attribute__((address_space(3))) unsigned int*)(unsigned int)(uintptr_t)l,
        16, 0, 0);
}

#define VM4 asm volatile("s_waitcnt vmcnt(4)" ::: "memory")
#define VM2 asm volatile("s_waitcnt vmcnt(2)" ::: "memory")
#define VM0 asm volatile("s_waitcnt vmcnt(0)" ::: "memory")
#define VMNOP do {} while (0)
#define BAR do { __builtin_amdgcn_s_barrier(); asm volatile("" ::: "memory"); } while (0)

__global__ __launch_bounds__(512, 2) void gemm256(const unsigned short* __restrict__ Xb,
                                                  const unsigned short* __restrict__ Wb,
                                                  const unsigned short* __restrict__ Xe,
                                                  const unsigned short* __restrict__ We,
                                                  const float* __restrict__ bias,
                                                  float* __restrict__ out) {
    extern __shared__ unsigned short lds[];

    const int nT = 512;                      // 32 x 16 tiles, %8==0 -> bijective XCD swizzle
    int bid = blockIdx.x;
    int swz = (bid & 7) * (nT >> 3) + (bid >> 3);
    int tm = swz >> 4, tn = swz & 15;
    int rowBase = tm * 256, colBase = tn * 256;

    int t = threadIdx.x;
    int lane = t & 63;
    int wid = t >> 6;
    int wm = wid >> 2;                       // 0..1 -> 128 rows
    int wn = wid & 3;                        // 0..3 -> 64 cols
    int frow = lane & 15;
    int koct = lane >> 4;
    int wmBase = wm * 128, wnBase = wn * 64;

    // staging: thread t -> row t>>3, dest chunk t&7; global source chunk (t&7)^(row&7)
    int srow = t >> 3;
    int schunk = ((t & 7) ^ (srow & 7)) << 3;
    const unsigned short* srcA0 = Xb + (size_t)(rowBase + srow) * IN_DIM + schunk;
    const unsigned short* srcB0 = Wb + (size_t)(colBase + srow) * IN_DIM + schunk;
    const unsigned short* srcAe = Xe + (size_t)(rowBase + srow) * K_EXT + schunk;
    const unsigned short* srcBe = We + (size_t)(colBase + srow) * K_EXT + schunk;

    f32x4 acc[8][4];
#pragma unroll
    for (int m = 0; m < 8; m++)
#pragma unroll
        for (int n = 0; n < 4; n++)
#pragma unroll
            for (int j = 0; j < 4; j++) acc[m][n][j] = 0.f;

#define RD_A(P_, MH, KS, DST) \
    _Pragma("unroll") for (int mm = 0; mm < 4; ++mm) { \
      int r_ = wmBase + (MH) * 64 + mm * 16 + frow; \
      int ch_ = ((KS) * 4 + koct) ^ (r_ & 7); \
      DST[mm] = *(const bf16x8*)&lds[(P_) * 32768 + r_ * 64 + ch_ * 8]; \
    }
#define RD_B(P_, KS, DST) \
    _Pragma("unroll") for (int nn = 0; nn < 4; ++nn) { \
      int r_ = wnBase + nn * 16 + frow; \
      int ch_ = ((KS) * 4 + koct) ^ (r_ & 7); \
      DST[nn] = *(const bf16x8*)&lds[(P_) * 32768 + 16384 + r_ * 64 + ch_ * 8]; \
    }
#define MFMA16(AF, BF, MH) \
    __builtin_amdgcn_s_setprio(1); \
    _Pragma("unroll") for (int mm = 0; mm < 4; ++mm) \
      _Pragma("unroll") for (int nn = 0; nn < 4; ++nn) \
        acc[(MH) * 4 + mm][nn] = __builtin_amdgcn_mfma_f32_16x16x32_bf16( \
            AF[mm], BF[nn], acc[(MH) * 4 + mm][nn], 0, 0, 0); \
    __builtin_amdgcn_s_setprio(0);

// Round-4 TILE verbatim, but source pointers/stride/offset are macro ARGS so every
// call site resolves them at compile time (no in-loop cndmask/branch).
// vmcnt invariant: entering a tile, 2 loads (its A1,A3) outstanding; ph0 VM4 publishes
// them; ph3 VM2 publishes the next tile's first 6.
#define TILE(P_, Q_, SA_, SB_, GS_, KO_, STG_, VMA_, VMB_) do { \
    bf16x8 a0_[4], a1_[4], b0_[4], b1_[4]; \
    RD_A(P_, 0, 0, a0_); RD_B(P_, 0, b0_); \
    if (STG_) { gload_lds16((SA_) + (KO_),                    &lds[(Q_) * 32768 + t * 8]); \
                gload_lds16((SA_) + (KO_) + 2 * (size_t)(GS_), &lds[(Q_) * 32768 + 8192 + t * 8]); \
                gload_lds16((SB_) + (KO_),                    &lds[(Q_) * 32768 + 16384 + t * 8]); \
                gload_lds16((SB_) + (KO_) + (size_t)(GS_),     &lds[(Q_) * 32768 + 20480 + t * 8]); } \
    VMA_; BAR; MFMA16(a0_, b0_, 0); BAR; \
    RD_A(P_, 1, 0, a1_); \
    if (STG_) { gload_lds16((SB_) + (KO_) + 2 * (size_t)(GS_), &lds[(Q_) * 32768 + 24576 + t * 8]); \
                gload_lds16((SB_) + (KO_) + 3 * (size_t)(GS_), &lds[(Q_) * 32768 + 28672 + t * 8]); \
                gload_lds16((SA_) + (KO_) + (size_t)(GS_),     &lds[(Q_) * 32768 + 4096 + t * 8]); \
                gload_lds16((SA_) + (KO_) + 3 * (size_t)(GS_), &lds[(Q_) * 32768 + 12288 + t * 8]); } \
    BAR; MFMA16(a1_, b0_, 1); BAR; \
    RD_A(P_, 0, 1, a0_); RD_B(P_, 1, b1_); \
    BAR; MFMA16(a0_, b1_, 0); BAR; \
    RD_A(P_, 1, 1, a1_); \
    VMB_; BAR; MFMA16(a1_, b1_, 1); BAR; \
  } while (0)

#define GSB ((size_t)64 * IN_DIM)

    // prologue: stage tile 0 into buf 0 (order A0,A2,B0..B3,A1,A3), publish first 6
    gload_lds16(srcA0,                         &lds[t * 8]);
    gload_lds16(srcA0 + (size_t)128 * IN_DIM,  &lds[8192 + t * 8]);
    gload_lds16(srcB0,                         &lds[16384 + t * 8]);
    gload_lds16(srcB0 + (size_t)64 * IN_DIM,   &lds[20480 + t * 8]);
    gload_lds16(srcB0 + (size_t)128 * IN_DIM,  &lds[24576 + t * 8]);
    gload_lds16(srcB0 + (size_t)192 * IN_DIM,  &lds[28672 + t * 8]);
    gload_lds16(srcA0 + (size_t)64 * IN_DIM,   &lds[4096 + t * 8]);
    gload_lds16(srcA0 + (size_t)192 * IN_DIM,  &lds[12288 + t * 8]);
    VM2; BAR;

    int kel = 0;
#pragma unroll 1
    for (int it = 0; it < 31; ++it) {        // tiles 0..61, staging 1..62 (all base)
        TILE(0, 1, srcA0, srcB0, GSB, kel + 64, 1, VM4, VM2); kel += 64;
        TILE(1, 0, srcA0, srcB0, GSB, kel + 64, 1, VM4, VM2); kel += 64;
    }
    // tail: all source selections compile-time
    TILE(0, 1, srcA0, srcB0, GSB, 4032, 1, VM4, VM2);   // tile 62, stages base tile 63
    TILE(1, 0, srcAe, srcBe, 8192, 0, 1, VM4, VM2);     // tile 63, stages ext tile 64 (cols 0..63)
    TILE(0, 1, srcAe, srcBe, 8192, 64, 1, VM4, VM2);    // tile 64, stages ext tile 65 (cols 64..127)
    TILE(1, 0, srcA0, srcB0, GSB, 0, 0, VM0, VMNOP);    // tile 65, last

    // ---- epilogue: out = acc + bias ----
    int rquad = koct << 2;
    float biasv[4];
#pragma unroll
    for (int n = 0; n < 4; n++) biasv[n] = bias[colBase + wnBase + n * 16 + frow];

#pragma unroll
    for (int m = 0; m < 8; m++) {
#pragma unroll
        for (int rg = 0; rg < 4; rg++) {
            int lr = wmBase + (m >> 2) * 64 + (m & 3) * 16 + rquad + rg;
            float* orow = out + (size_t)(rowBase + lr) * OUT_DIM;
#pragma unroll
            for (int n = 0; n < 4; n++) {
                int lc = wnBase + n * 16 + frow;
                orow[colBase + lc] = acc[m][n][rg] + biasv[n];
            }
        }
    }
}

extern "C" void kernel_launch(void* const* d_in, const int* in_sizes, int n_in,
                              void* d_out, int out_size, void* d_ws, size_t ws_size,
                              hipStream_t stream) {
    const float* x = (const float*)d_in[0];
    const float* W = (const float*)d_in[1];
    const float* bias = (const float*)d_in[2];
    const float* Abuf = (const float*)d_in[3];
    const float* Bbuf = (const float*)d_in[4];   // [1, A, OUT, R]
    const int* widx = (const int*)d_in[5];
    float* out = (float*)d_out;

    size_t xbf_elems = (size_t)S_DIM * IN_DIM;
    size_t wbf_elems = (size_t)OUT_DIM * IN_DIM;
    size_t abf_elems = (size_t)8 * 16 * IN_DIM;
    size_t xe_elems = (size_t)S_DIM * K_EXT;
    size_t we_elems = (size_t)OUT_DIM * K_EXT;
    size_t need = (xbf_elems + wbf_elems + abf_elems + xe_elems + we_elems) * 2;
    if (ws_size < need) return;

    unsigned short* xbf = (unsigned short*)d_ws;
    unsigned short* wbf = xbf + xbf_elems;
    unsigned short* abf = wbf + wbf_elems;
    unsigned short* xe = abf + abf_elems;
    unsigned short* we = xe + xe_elems;

    hipFuncSetAttribute(reinterpret_cast<const void*>(gemm256),
                        hipFuncAttributeMaxDynamicSharedMemorySize, 131072);

    convert_w<<<2048, 256, 0, stream>>>(W, wbf, (int)(wbf_elems / 4));
    convert_w<<<512, 256, 0, stream>>>(Abuf, abf, (int)(abf_elems / 4));
    build_we<<<128, 256, 0, stream>>>(Bbuf, we);
    xak<<<256, 512, 0, stream>>>(x, abf, widx, xbf, xe);
    gemm256<<<512, 512, 131072, stream>>>(xbf, wbf, xe, we, bias, out);
}

// Round 7
// 329.034 us; speedup vs baseline: 1.1824x; 1.0010x over previous
//
#include <hip/hip_runtime.h>
#include <stdint.h>

#define S_DIM 8192
#define IN_DIM 4096
#define OUT_DIM 4096
#define K_EXT 128
#define SCALING 0.5f

typedef __attribute__((ext_vector_type(4))) float f32x4;
typedef __attribute__((ext_vector_type(8))) __bf16 bf16x8;

__device__ __forceinline__ unsigned short f2bf(float f) {
    union { float f; uint32_t u; } v; v.f = f;
    uint32_t u = v.u;
    u += 0x7fffu + ((u >> 16) & 1u);   // RNE
    return (unsigned short)(u >> 16);
}

// ---------------- Kernel 1: f32 -> bf16 (grid-stride; used for W and A) ----------------
__global__ __launch_bounds__(256) void convert_w(const float* __restrict__ in,
                                                 unsigned short* __restrict__ out, int n4) {
    int i = blockIdx.x * blockDim.x + threadIdx.x;
    int stride = gridDim.x * blockDim.x;
    for (; i < n4; i += stride) {
        float4 v = ((const float4*)in)[i];
        ushort4 o;
        o.x = f2bf(v.x); o.y = f2bf(v.y); o.z = f2bf(v.z); o.w = f2bf(v.w);
        ((ushort4*)out)[i] = o;
    }
}

// ---------------- Kernel 2: we[o][a*16+r] = bf16(0.5 * B[a][o][r]) ----------------
__global__ __launch_bounds__(256) void build_we(const float* __restrict__ B,
                                                unsigned short* __restrict__ we) {
    int i = blockIdx.x * 256 + threadIdx.x;   // 0..32767 -> (o, a)
    int o = i >> 3, a = i & 7;
    const float* src = B + ((size_t)a * OUT_DIM + o) * 16;
    unsigned short* dst = we + (size_t)o * K_EXT + a * 16;
#pragma unroll
    for (int r = 0; r < 16; r += 4) {
        float4 v = *(const float4*)(src + r);
        ushort4 u;
        u.x = f2bf(SCALING * v.x); u.y = f2bf(SCALING * v.y);
        u.z = f2bf(SCALING * v.z); u.w = f2bf(SCALING * v.w);
        *(ushort4*)(dst + r) = u;
    }
}

// ------- Kernel 3: x f32->bf16 + xe[s][a*16+r] = (a==widx[s]) ? x[s,:].A[a,r,:] : 0 -------
__global__ __launch_bounds__(512) void xak(const float* __restrict__ x,
                                           const unsigned short* __restrict__ Abf,
                                           const int* __restrict__ widx,
                                           unsigned short* __restrict__ xbf,
                                           unsigned short* __restrict__ xe) {
    __shared__ unsigned short xs[32 * 64];    // 4 KB, swizzled
    __shared__ unsigned short as_[128 * 64];  // 16 KB, swizzled
    int s0 = blockIdx.x * 32;
    int t = threadIdx.x;
    int lane = t & 63, w = t >> 6;
    int wr = w & 1, wc = w >> 1;
    int frow = lane & 15, koct = lane >> 4;

    f32x4 acc[2];
#pragma unroll
    for (int n = 0; n < 2; ++n)
#pragma unroll
        for (int j = 0; j < 4; ++j) acc[n][j] = 0.f;

    int xrow = t >> 4, xf4 = t & 15;
    const float* xsrc = x + (size_t)(s0 + xrow) * IN_DIM + xf4 * 4;
    unsigned short* xdst = xbf + (size_t)(s0 + xrow) * IN_DIM + xf4 * 4;
    int xsd = xrow * 64 + ((xf4 * 4) ^ ((xrow & 7) << 3));

    for (int kt = 0; kt < 64; ++kt) {
        int k0 = kt * 64;
        __syncthreads();
        {
            float4 xv = *(const float4*)(xsrc + k0);
            ushort4 o;
            o.x = f2bf(xv.x); o.y = f2bf(xv.y); o.z = f2bf(xv.z); o.w = f2bf(xv.w);
            *(ushort4*)(xdst + k0) = o;
            *(ushort4*)&xs[xsd] = o;
        }
#pragma unroll
        for (int i = 0; i < 2; ++i) {
            int c = i * 512 + t;
            int aj = c >> 3, ch = c & 7;
            bf16x8 av = *(const bf16x8*)(Abf + (size_t)aj * IN_DIM + k0 + ch * 8);
            *(bf16x8*)&as_[aj * 64 + ((ch ^ (aj & 7)) << 3)] = av;
        }
        __syncthreads();
        bf16x8 xf[2], af[2][2];
#pragma unroll
        for (int ks = 0; ks < 2; ++ks) {
            int r = wr * 16 + frow;
            int ch = koct + ks * 4;
            xf[ks] = *(const bf16x8*)&xs[r * 64 + ((ch ^ (r & 7)) << 3)];
        }
#pragma unroll
        for (int nn = 0; nn < 2; ++nn)
#pragma unroll
            for (int ks = 0; ks < 2; ++ks) {
                int rj = wc * 32 + nn * 16 + frow;
                int ch = koct + ks * 4;
                af[nn][ks] = *(const bf16x8*)&as_[rj * 64 + ((ch ^ (rj & 7)) << 3)];
            }
#pragma unroll
        for (int nn = 0; nn < 2; ++nn)
#pragma unroll
            for (int ks = 0; ks < 2; ++ks)
                acc[nn] = __builtin_amdgcn_mfma_f32_16x16x32_bf16(xf[ks], af[nn][ks], acc[nn], 0, 0, 0);
    }
#pragma unroll
    for (int rg = 0; rg < 4; ++rg) {
        int s = s0 + wr * 16 + koct * 4 + rg;
        int aidx = widx[s];
#pragma unroll
        for (int nn = 0; nn < 2; ++nn) {
            int a = wc * 2 + nn;
            unsigned short v = (a == aidx) ? f2bf(acc[nn][rg]) : (unsigned short)0;
            xe[(size_t)s * K_EXT + a * 16 + frow] = v;
        }
    }
}

// ---------------- Kernel 4: 256x256 bf16 MFMA GEMM over K=4224, counted-vmcnt ----------------
__device__ __forceinline__ void gload_lds16(const void* g, void* l) {
    __builtin_amdgcn_global_load_lds(
        (const __attribute__((address_space(1))) unsigned int*)(uintptr_t)g,
        (__attribute__((address_space(3))) unsigned int*)(unsigned int)(uintptr_t)l,
        16, 0, 0);
}

#define VM4 asm volatile("s_waitcnt vmcnt(4)" ::: "memory")
#define VM2 asm volatile("s_waitcnt vmcnt(2)" ::: "memory")
#define VM0 asm volatile("s_waitcnt vmcnt(0)" ::: "memory")
#define VMNOP do {} while (0)
#define BAR do { __builtin_amdgcn_s_barrier(); asm volatile("" ::: "memory"); } while (0)

__global__ __launch_bounds__(512, 2) void gemm256(const unsigned short* __restrict__ Xb,
                                                  const unsigned short* __restrict__ Wb,
                                                  const unsigned short* __restrict__ Xe,
                                                  const unsigned short* __restrict__ We,
                                                  const float* __restrict__ bias,
                                                  float* __restrict__ out) {
    extern __shared__ unsigned short lds[];

    const int nT = 512;                      // 32 x 16 tiles, %8==0 -> bijective XCD swizzle
    int bid = blockIdx.x;
    int swz = (bid & 7) * (nT >> 3) + (bid >> 3);
    int tm = swz >> 4, tn = swz & 15;
    int rowBase = tm * 256, colBase = tn * 256;

    int t = threadIdx.x;
    int lane = t & 63;
    int wid = t >> 6;
    int wm = wid >> 2;                       // 0..1 -> 128 rows
    int wn = wid & 3;                        // 0..3 -> 64 cols
    int frow = lane & 15;
    int koct = lane >> 4;
    int wmBase = wm * 128, wnBase = wn * 64;

    // ---- hoisted LDS read base pointers (8 VGPRs, all reads get compile-time immediates) ----
    // row term: (rows)*64 elems; XOR chunk term depends only on frow&7 (mm/MH/nn are x8-row multiples)
    int ch0 = (koct ^ (frow & 7)) << 3;          // ks0 chunk, elements
    int ch1 = ((koct + 4) ^ (frow & 7)) << 3;    // ks1 chunk, elements
    const unsigned short* pA00 = lds + (wmBase + frow) * 64 + ch0;           // parity0, ks0
    const unsigned short* pA01 = lds + (wmBase + frow) * 64 + ch1;           // parity0, ks1
    const unsigned short* pA10 = pA00 + 32768;                               // parity1, ks0
    const unsigned short* pA11 = pA01 + 32768;                               // parity1, ks1
    const unsigned short* pB00 = lds + 16384 + (wnBase + frow) * 64 + ch0;
    const unsigned short* pB01 = lds + 16384 + (wnBase + frow) * 64 + ch1;
    const unsigned short* pB10 = pB00 + 32768;
    const unsigned short* pB11 = pB01 + 32768;

    // ---- staging: uniform base (SGPR-foldable) + 32-bit per-lane offset ----
    int srow = t >> 3;
    int schunk = ((t & 7) ^ (srow & 7)) << 3;
    const unsigned short* aBase = Xb + (size_t)rowBase * IN_DIM;
    const unsigned short* bBase = Wb + (size_t)colBase * IN_DIM;
    const unsigned short* aeBase = Xe + (size_t)rowBase * K_EXT;
    const unsigned short* beBase = We + (size_t)colBase * K_EXT;
    uint32_t offB_ = (uint32_t)(srow * IN_DIM + schunk);     // base-K per-lane offset
    uint32_t offE_ = (uint32_t)(srow * K_EXT + schunk);      // ext-K per-lane offset

    f32x4 acc[8][4];
#pragma unroll
    for (int m = 0; m < 8; m++)
#pragma unroll
        for (int n = 0; n < 4; n++)
#pragma unroll
            for (int j = 0; j < 4; j++) acc[m][n][j] = 0.f;

// RD_A(parity, ks, MH, DST): token-pasted base pointer + immediate offsets only
#define RD_A(P_, KS_, MH, DST) \
    _Pragma("unroll") for (int mm = 0; mm < 4; ++mm) \
      DST[mm] = *(const bf16x8*)(pA##P_##KS_ + (MH) * 4096 + mm * 1024);
#define RD_B(P_, KS_, DST) \
    _Pragma("unroll") for (int nn = 0; nn < 4; ++nn) \
      DST[nn] = *(const bf16x8*)(pB##P_##KS_ + nn * 1024);
#define MFMA16(AF, BF, MH) \
    __builtin_amdgcn_s_setprio(1); \
    _Pragma("unroll") for (int mm = 0; mm < 4; ++mm) \
      _Pragma("unroll") for (int nn = 0; nn < 4; ++nn) \
        acc[(MH) * 4 + mm][nn] = __builtin_amdgcn_mfma_f32_16x16x32_bf16( \
            AF[mm], BF[nn], acc[(MH) * 4 + mm][nn], 0, 0, 0); \
    __builtin_amdgcn_s_setprio(0);

// Round-6 TILE schedule verbatim; only addressing differs (BA_/BB_ uniform bases,
// OFF_ per-lane 32-bit offset, GS_ row-group stride, KO_ compile-time-resolvable k offset).
// vmcnt invariant: entering a tile, 2 loads (its A1,A3) outstanding; ph0 VM4 publishes
// them; ph3 VM2 publishes the next tile's first 6.
#define TILE(P_, Q_, BA_, BB_, OFF_, GS_, KO_, STG_, VMA_, VMB_) do { \
    bf16x8 a0_[4], a1_[4], b0_[4], b1_[4]; \
    RD_A(P_, 0, 0, a0_); RD_B(P_, 0, b0_); \
    if (STG_) { gload_lds16((BA_) + (KO_) + (OFF_),                    &lds[(Q_) * 32768 + t * 8]); \
                gload_lds16((BA_) + (KO_) + 2 * (size_t)(GS_) + (OFF_), &lds[(Q_) * 32768 + 8192 + t * 8]); \
                gload_lds16((BB_) + (KO_) + (OFF_),                    &lds[(Q_) * 32768 + 16384 + t * 8]); \
                gload_lds16((BB_) + (KO_) + (size_t)(GS_) + (OFF_),     &lds[(Q_) * 32768 + 20480 + t * 8]); } \
    VMA_; BAR; MFMA16(a0_, b0_, 0); BAR; \
    RD_A(P_, 0, 1, a1_); \
    if (STG_) { gload_lds16((BB_) + (KO_) + 2 * (size_t)(GS_) + (OFF_), &lds[(Q_) * 32768 + 24576 + t * 8]); \
                gload_lds16((BB_) + (KO_) + 3 * (size_t)(GS_) + (OFF_), &lds[(Q_) * 32768 + 28672 + t * 8]); \
                gload_lds16((BA_) + (KO_) + (size_t)(GS_) + (OFF_),     &lds[(Q_) * 32768 + 4096 + t * 8]); \
                gload_lds16((BA_) + (KO_) + 3 * (size_t)(GS_) + (OFF_), &lds[(Q_) * 32768 + 12288 + t * 8]); } \
    BAR; MFMA16(a1_, b0_, 1); BAR; \
    RD_A(P_, 1, 0, a0_); RD_B(P_, 1, b1_); \
    BAR; MFMA16(a0_, b1_, 0); BAR; \
    RD_A(P_, 1, 1, a1_); \
    VMB_; BAR; MFMA16(a1_, b1_, 1); BAR; \
  } while (0)

#define GSB ((size_t)64 * IN_DIM)

    // prologue: stage tile 0 into buf 0 (order A0,A2,B0..B3,A1,A3), publish first 6
    gload_lds16(aBase + offB_,                         &lds[t * 8]);
    gload_lds16(aBase + (size_t)128 * IN_DIM + offB_,  &lds[8192 + t * 8]);
    gload_lds16(bBase + offB_,                         &lds[16384 + t * 8]);
    gload_lds16(bBase + (size_t)64 * IN_DIM + offB_,   &lds[20480 + t * 8]);
    gload_lds16(bBase + (size_t)128 * IN_DIM + offB_,  &lds[24576 + t * 8]);
    gload_lds16(bBase + (size_t)192 * IN_DIM + offB_,  &lds[28672 + t * 8]);
    gload_lds16(aBase + (size_t)64 * IN_DIM + offB_,   &lds[4096 + t * 8]);
    gload_lds16(aBase + (size_t)192 * IN_DIM + offB_,  &lds[12288 + t * 8]);
    VM2; BAR;

    int kel = 0;
#pragma unroll 1
    for (int it = 0; it < 31; ++it) {        // tiles 0..61, staging 1..62 (all base)
        TILE(0, 1, aBase, bBase, offB_, GSB, kel + 64, 1, VM4, VM2); kel += 64;
        TILE(1, 0, aBase, bBase, offB_, GSB, kel + 64, 1, VM4, VM2); kel += 64;
    }
    // tail: all source selections compile-time
    TILE(0, 1, aBase, bBase, offB_, GSB, 4032, 1, VM4, VM2);     // tile 62, stages base tile 63
    TILE(1, 0, aeBase, beBase, offE_, 8192, 0, 1, VM4, VM2);     // tile 63, stages ext tile 64
    TILE(0, 1, aeBase, beBase, offE_, 8192, 64, 1, VM4, VM2);    // tile 64, stages ext tile 65
    TILE(1, 0, aBase, bBase, offB_, GSB, 0, 0, VM0, VMNOP);      // tile 65, last

    // ---- epilogue: out = acc + bias ----
    int rquad = koct << 2;
    float biasv[4];
#pragma unroll
    for (int n = 0; n < 4; n++) biasv[n] = bias[colBase + wnBase + n * 16 + frow];

#pragma unroll
    for (int m = 0; m < 8; m++) {
#pragma unroll
        for (int rg = 0; rg < 4; rg++) {
            int lr = wmBase + (m >> 2) * 64 + (m & 3) * 16 + rquad + rg;
            float* orow = out + (size_t)(rowBase + lr) * OUT_DIM;
#pragma unroll
            for (int n = 0; n < 4; n++) {
                int lc = wnBase + n * 16 + frow;
                orow[colBase + lc] = acc[m][n][rg] + biasv[n];
            }
        }
    }
}

extern "C" void kernel_launch(void* const* d_in, const int* in_sizes, int n_in,
                              void* d_out, int out_size, void* d_ws, size_t ws_size,
                              hipStream_t stream) {
    const float* x = (const float*)d_in[0];
    const float* W = (const float*)d_in[1];
    const float* bias = (const float*)d_in[2];
    const float* Abuf = (const float*)d_in[3];
    const float* Bbuf = (const float*)d_in[4];   // [1, A, OUT, R]
    const int* widx = (const int*)d_in[5];
    float* out = (float*)d_out;

    size_t xbf_elems = (size_t)S_DIM * IN_DIM;
    size_t wbf_elems = (size_t)OUT_DIM * IN_DIM;
    size_t abf_elems = (size_t)8 * 16 * IN_DIM;
    size_t xe_elems = (size_t)S_DIM * K_EXT;
    size_t we_elems = (size_t)OUT_DIM * K_EXT;
    size_t need = (xbf_elems + wbf_elems + abf_elems + xe_elems + we_elems) * 2;
    if (ws_size < need) return;

    unsigned short* xbf = (unsigned short*)d_ws;
    unsigned short* wbf = xbf + xbf_elems;
    unsigned short* abf = wbf + wbf_elems;
    unsigned short* xe = abf + abf_elems;
    unsigned short* we = xe + xe_elems;

    hipFuncSetAttribute(reinterpret_cast<const void*>(gemm256),
                        hipFuncAttributeMaxDynamicSharedMemorySize, 131072);

    convert_w<<<2048, 256, 0, stream>>>(W, wbf, (int)(wbf_elems / 4));
    convert_w<<<512, 256, 0, stream>>>(Abuf, abf, (int)(abf_elems / 4));
    build_we<<<128, 256, 0, stream>>>(Bbuf, we);
    xak<<<256, 512, 0, stream>>>(x, abf, widx, xbf, xe);
    gemm256<<<512, 512, 131072, stream>>>(xbf, wbf, xe, we, bias, out);
}